// Round 3
// baseline (210.977 us; speedup 1.0000x reference)
//
#include <hip/hip_runtime.h>
#include <hip/hip_bf16.h>
#include <stdint.h>
#include <math.h>

#define SEQ 2048
#define DM 1024
#define NH 16
#define DK 64

typedef __attribute__((ext_vector_type(8))) short short8;
typedef __attribute__((ext_vector_type(4))) short short4v;
typedef __attribute__((ext_vector_type(4))) float f32x4;

__device__ __forceinline__ float bf2f(unsigned short s) {
  unsigned u = ((unsigned)s) << 16; float f; __builtin_memcpy(&f, &u, 4); return f;
}
__device__ __forceinline__ unsigned short f2bf(float f) {
  unsigned u; __builtin_memcpy(&u, &f, 4);
  u += 0x7FFFu + ((u >> 16) & 1u);          // RNE
  return (unsigned short)(u >> 16);
}
__device__ __forceinline__ unsigned cvt_pk_bf16(float lo, float hi) {
  unsigned r;
  asm("v_cvt_pk_bf16_f32 %0, %1, %2" : "=v"(r) : "v"(lo), "v"(hi));
  return r;   // [bf16(hi)<<16 | bf16(lo)]
}
__device__ __forceinline__ f32x4 mfma16(short8 a, short8 b, f32x4 c) {
  return __builtin_amdgcn_mfma_f32_16x16x32_bf16(a, b, c, 0, 0, 0);
}
__device__ __forceinline__ void gload_lds16(const void* g, void* l) {
  __builtin_amdgcn_global_load_lds((const __attribute__((address_space(1))) void*)g,
                                   (__attribute__((address_space(3))) void*)l, 16, 0, 0);
}

// ---------------- prep: fp32 -> bf16 for x and the 4 weight matrices ----------------
__global__ __launch_bounds__(256) void prep_kernel(
    const float* __restrict__ x, const float* __restrict__ Wq,
    const float* __restrict__ Wk, const float* __restrict__ Wv,
    const float* __restrict__ Wo, __hip_bfloat16* __restrict__ xb,
    __hip_bfloat16* __restrict__ Wb) {
  int chunk = blockIdx.x * 256 + threadIdx.x;   // 1,048,576 chunks of 8 elems
  const float* src; __hip_bfloat16* dst;
  if (chunk < 524288) { src = x + (size_t)chunk * 8; dst = xb + (size_t)chunk * 8; }
  else {
    int wc = chunk - 524288; int wi = wc >> 17; int wo_ = wc & 131071;
    const float* Ws = (wi == 0) ? Wq : (wi == 1) ? Wk : (wi == 2) ? Wv : Wo;
    src = Ws + (size_t)wo_ * 8; dst = Wb + (size_t)wi * 1048576 + (size_t)wo_ * 8;
  }
  float4 a = *(const float4*)src; float4 b = *(const float4*)(src + 4);
  union { short8 v; unsigned short e[8]; } u;
  u.e[0] = f2bf(a.x); u.e[1] = f2bf(a.y); u.e[2] = f2bf(a.z); u.e[3] = f2bf(a.w);
  u.e[4] = f2bf(b.x); u.e[5] = f2bf(b.y); u.e[6] = f2bf(b.z); u.e[7] = f2bf(b.w);
  *(short8*)dst = u.v;
}

// ---------------- RoPE cos/sin table: [2048][32] float2 ----------------
__global__ __launch_bounds__(256) void rope_table_kernel(float2* __restrict__ tab) {
  int idx = blockIdx.x * 256 + threadIdx.x;   // 65536
  int s = idx >> 5, i = idx & 31;
  float fr = powf(10000.0f, -(float)i * (1.0f / 32.0f));
  float ang = (float)s * fr;
  tab[idx] = make_float2(cosf(ang), sinf(ang));
}

// ---------------- GEMM: C[M][N] = A[M][1024] @ W[N][1024]^T  (bf16 in, fp32 acc) ----
// 128xBN tile, BK=32, 4 waves (2x2), global_load_lds staging, XOR-swizzled LDS.
// VSPLIT=1: blocks with n0>=2048 (the V part of QKV) write TRANSPOSED to Vt instead.
template<int OUTF32, int BN, int VSPLIT>
__global__ __launch_bounds__(256) void gemm_bt(
    const __hip_bfloat16* __restrict__ A, const __hip_bfloat16* __restrict__ W,
    void* __restrict__ C, const int N, __hip_bfloat16* __restrict__ Vt) {
  constexpr int NI = BN / 32;       // B-frags per wave
  constexpr int WN = BN / 2;        // per-wave N extent
  __shared__ alignas(16) __hip_bfloat16 As[128 * 32];
  __shared__ alignas(16) __hip_bfloat16 Bs[BN * 32];
  const int t = threadIdx.x;
  const int m0 = blockIdx.x * 128, n0 = blockIdx.y * BN;
  const int w = t >> 6, lane = t & 63, l15 = lane & 15, hi = lane >> 4;
  const int wm = w >> 1, wn = w & 1;
  const int srow = t >> 2, scs = (t & 3) ^ (srow & 3);   // inverse-swizzled source chunk
  const __hip_bfloat16* aSrcA = A + (size_t)(m0 + srow) * DM + scs * 8;
  const __hip_bfloat16* aSrcB = aSrcA + (size_t)64 * DM;
  const __hip_bfloat16* bSrcA = W + (size_t)(n0 + srow) * DM + scs * 8;
  const __hip_bfloat16* bSrcB = bSrcA + (size_t)64 * DM;
  char* aDstA = (char*)As + t * 16; char* aDstB = (char*)As + (t + 256) * 16;
  char* bDstA = (char*)Bs + t * 16; char* bDstB = (char*)Bs + (t + 256) * 16;
  const int r3 = l15 & 3;
  int aoff[4], boff[NI];
#pragma unroll
  for (int i = 0; i < 4; ++i)
    aoff[i] = (wm * 64 + i * 16 + l15) * 64 + ((hi ^ r3) * 16);   // bytes
#pragma unroll
  for (int i = 0; i < NI; ++i)
    boff[i] = (wn * WN + i * 16 + l15) * 64 + ((hi ^ r3) * 16);
  f32x4 acc[4][NI] = {};
  for (int kt = 0; kt < DM; kt += 32) {
    gload_lds16(aSrcA + kt, aDstA);
    gload_lds16(aSrcB + kt, aDstB);
    gload_lds16(bSrcA + kt, bDstA);
    if (BN == 128) gload_lds16(bSrcB + kt, bDstB);
    __syncthreads();
    short8 af[4], bfr[NI];
#pragma unroll
    for (int i = 0; i < 4; ++i) af[i] = *(const short8*)((const char*)As + aoff[i]);
#pragma unroll
    for (int i = 0; i < NI; ++i) bfr[i] = *(const short8*)((const char*)Bs + boff[i]);
#pragma unroll
    for (int mi = 0; mi < 4; ++mi)
#pragma unroll
      for (int ni = 0; ni < NI; ++ni)
        acc[mi][ni] = mfma16(af[mi], bfr[ni], acc[mi][ni]);
    __syncthreads();
  }
  const int mBase = m0 + wm * 64, nBase = n0 + wn * WN;
  if (VSPLIT && n0 >= 2048) {
    // V part: write transposed Vt[(b*1024 + (n-2048))*2048 + s], 4 consecutive s / lane
#pragma unroll
    for (int mi = 0; mi < 4; ++mi)
#pragma unroll
      for (int ni = 0; ni < NI; ++ni) {
        int m = mBase + mi * 16 + hi * 4, n = nBase + ni * 16 + l15;
        int bb = m >> 11, s = m & 2047, hd = n - 2048;
        uint2 pk;
        pk.x = cvt_pk_bf16(acc[mi][ni][0], acc[mi][ni][1]);
        pk.y = cvt_pk_bf16(acc[mi][ni][2], acc[mi][ni][3]);
        *(uint2*)(Vt + ((size_t)(bb * 1024 + hd) * 2048 + s)) = pk;
      }
  } else if (OUTF32) {
    float* Cf = (float*)C;
#pragma unroll
    for (int mi = 0; mi < 4; ++mi)
#pragma unroll
      for (int ni = 0; ni < NI; ++ni) {
        int m = mBase + mi * 16 + hi * 4, n = nBase + ni * 16 + l15;
#pragma unroll
        for (int r = 0; r < 4; ++r)
          Cf[(size_t)(m + r) * N + n] = acc[mi][ni][r];
      }
  } else {
    unsigned short* Cb = (unsigned short*)C;
#pragma unroll
    for (int mi = 0; mi < 4; ++mi)
#pragma unroll
      for (int ni = 0; ni < NI; ++ni) {
        int m = mBase + mi * 16 + hi * 4, n = nBase + ni * 16 + l15;
#pragma unroll
        for (int r = 0; r < 4; ++r)
          Cb[(size_t)(m + r) * N + n] = f2bf(acc[mi][ni][r]);
      }
  }
}

// ---------------- RoPE: rotate Q (cols 0..1023) and K (cols 1024..2047) in place ----
__global__ __launch_bounds__(256) void rope_kernel(
    __hip_bfloat16* __restrict__ QKV, const float2* __restrict__ tab) {
  int chunk = blockIdx.x * 256 + threadIdx.x;   // 4096 rows * 256 chunks
  int row = chunk >> 8; int c0 = (chunk & 255) << 3;
  int s = row & (SEQ - 1);
  const float2* tb = tab + s * 32 + ((c0 & 63) >> 1);
  __hip_bfloat16* p = QKV + (size_t)row * 3072 + c0;
  union { short8 v; unsigned short e[8]; } u; u.v = *(const short8*)p;
  union { short8 v; unsigned short e[8]; } o;
#pragma unroll
  for (int k = 0; k < 4; ++k) {
    float2 cs = tb[k];
    float x1 = bf2f(u.e[2 * k]), x2 = bf2f(u.e[2 * k + 1]);
    o.e[2 * k]     = f2bf(cs.x * x1 - cs.y * x2);
    o.e[2 * k + 1] = f2bf(cs.y * x1 + cs.x * x2);
  }
  *(short8*)p = o.v;
}

// ---------------- Flash attention (causal), swapped QK^T, online softmax ----------
// R3: counted-vmcnt double-barrier pipeline (prefetch never drained in-loop),
// diag tile peeled (mask-free main loop), exp2-domain softmax, defer-max (T13),
// cvt_pk_bf16 packing (T12 primitive), setprio around MFMA (T5).
__global__ __launch_bounds__(256) void attn_kernel(
    const __hip_bfloat16* __restrict__ QKV, const __hip_bfloat16* __restrict__ Vt,
    __hip_bfloat16* __restrict__ Ao) {
  const int id = blockIdx.x;
  const int bh = (id & 7) * 4 + ((id >> 3) & 3);   // id%8 constant per bh -> same XCD
  const int qt = 31 - (id >> 5);                   // heavy blocks dispatch first
  const int b = bh >> 4, h = bh & 15;
  __shared__ alignas(16) __hip_bfloat16 Ks[2][64 * 64];
  __shared__ alignas(16) __hip_bfloat16 Vs[2][64 * 64];
  const int t = threadIdx.x, w = t >> 6, lane = t & 63, l15 = lane & 15, hi = lane >> 4;
  const int qrow = qt * 64 + w * 16 + l15;
  const __hip_bfloat16* Qp = QKV + (size_t)(b * SEQ + qrow) * 3072 + h * 64 + hi * 8;
  const short8 qf0 = *(const short8*)Qp;          // B-op frag, d = 0..31
  const short8 qf1 = *(const short8*)(Qp + 32);   // d = 32..63
  const int sr = t >> 3, sc = t & 7, scs = sc ^ (sr & 7);
  const __hip_bfloat16* kSrcA = QKV + (size_t)(b * SEQ + sr) * 3072 + DM + h * 64 + scs * 8;
  const __hip_bfloat16* kSrcB = kSrcA + (size_t)32 * 3072;
  const __hip_bfloat16* vSrcA = Vt + ((size_t)bh * 64 + sr) * SEQ + scs * 8;
  const __hip_bfloat16* vSrcB = vSrcA + (size_t)32 * SEQ;
  char* kDstA = (char*)Ks + t * 16;  char* kDstB = (char*)Ks + (t + 256) * 16;
  char* vDstA = (char*)Vs + t * 16;  char* vDstB = (char*)Vs + (t + 256) * 16;
  const int r7 = l15 & 7;
  constexpr float SC = 0.18033688f;        // 0.125 * log2(e)
  constexpr float THR = 11.541560f;        // 8 nats in log2
  f32x4 ot[4] = {};
  float m_run = -INFINITY, l_run = 0.0f;

  // stage tile 0 -> buf0 (stays in flight; counted wait in first iter / drain block)
  gload_lds16(kSrcA, kDstA);
  gload_lds16(kSrcB, kDstB);
  gload_lds16(vSrcA, vDstA);
  gload_lds16(vSrcB, vDstB);

  const int srcA = ((hi & 1) << 5) + l15;   // P-redistribute source lanes
  const int srcB = srcA + 16;

  for (int kvt = 0; kvt < qt; ++kvt) {
    const int cur = kvt & 1;
    // stage kvt+1 into the other buffer (its previous readers finished before
    // the trailing barrier of iter kvt-1)
    const size_t ko = (size_t)((kvt + 1) * 64) * 3072;
    const int vo = (kvt + 1) * 64;
    gload_lds16(kSrcA + ko, kDstA + (cur ^ 1) * 8192);
    gload_lds16(kSrcB + ko, kDstB + (cur ^ 1) * 8192);
    gload_lds16(vSrcA + vo, vDstA + (cur ^ 1) * 8192);
    gload_lds16(vSrcB + vo, vDstB + (cur ^ 1) * 8192);
    // counted wait: my 4 older loads (tile kvt) done; 4 newest stay in flight.
    __builtin_amdgcn_sched_barrier(0);
    asm volatile("s_waitcnt vmcnt(4)" ::: "memory");
    __builtin_amdgcn_s_barrier();            // now ALL waves' tile-kvt loads landed
    __builtin_amdgcn_sched_barrier(0);

    const char* Kbase = (const char*)Ks + cur * 8192;
    const char* Vbase = (const char*)Vs + cur * 8192;
    float p[4][4];
    __builtin_amdgcn_s_setprio(1);
#pragma unroll
    for (int mc = 0; mc < 4; ++mc) {
      const char* rb = Kbase + (mc * 16 + l15) * 128;
      short8 a0 = *(const short8*)(rb + ((hi ^ r7) * 16));
      short8 a1 = *(const short8*)(rb + (((4 + hi) ^ r7) * 16));
      f32x4 st = {};
      st = mfma16(a0, qf0, st);   // S^T[kv][q], d = 0..31
      st = mfma16(a1, qf1, st);   // d = 32..63
#pragma unroll
      for (int r = 0; r < 4; ++r) p[mc][r] = st[r] * SC;
    }
    __builtin_amdgcn_s_setprio(0);
    float mt = -INFINITY;
#pragma unroll
    for (int mc = 0; mc < 4; ++mc)
#pragma unroll
      for (int r = 0; r < 4; ++r) mt = fmaxf(mt, p[mc][r]);
    mt = fmaxf(mt, __shfl_xor(mt, 16, 64));
    mt = fmaxf(mt, __shfl_xor(mt, 32, 64));
    if (!__all(mt <= m_run + THR)) {         // defer-max: rescale only on real growth
      const float m_new = fmaxf(m_run, mt);
      const float al = exp2f(m_run - m_new);
      l_run *= al;
#pragma unroll
      for (int d = 0; d < 4; ++d) ot[d] *= al;
      m_run = m_new;
    }
    float ls = 0.0f;
#pragma unroll
    for (int mc = 0; mc < 4; ++mc)
#pragma unroll
      for (int r = 0; r < 4; ++r) { float e = exp2f(p[mc][r] - m_run); p[mc][r] = e; ls += e; }
    ls += __shfl_xor(ls, 16, 64);
    ls += __shfl_xor(ls, 32, 64);
    l_run += ls;
    // pack P to bf16 pairs, redistribute to PV B-operand layout
    unsigned pu[4][2];
#pragma unroll
    for (int mc = 0; mc < 4; ++mc) {
      pu[mc][0] = cvt_pk_bf16(p[mc][0], p[mc][1]);
      pu[mc][1] = cvt_pk_bf16(p[mc][2], p[mc][3]);
    }
    __builtin_amdgcn_s_setprio(1);
#pragma unroll
    for (int ks = 0; ks < 2; ++ks) {
      unsigned a0 = (unsigned)__shfl((int)pu[2 * ks][0], srcA, 64);
      unsigned a1 = (unsigned)__shfl((int)pu[2 * ks][1], srcA, 64);
      unsigned a2 = (unsigned)__shfl((int)pu[2 * ks][0], srcB, 64);
      unsigned a3 = (unsigned)__shfl((int)pu[2 * ks][1], srcB, 64);
      unsigned b0 = (unsigned)__shfl((int)pu[2 * ks + 1][0], srcA, 64);
      unsigned b1 = (unsigned)__shfl((int)pu[2 * ks + 1][1], srcA, 64);
      unsigned b2 = (unsigned)__shfl((int)pu[2 * ks + 1][0], srcB, 64);
      unsigned b3 = (unsigned)__shfl((int)pu[2 * ks + 1][1], srcB, 64);
      union { unsigned u[4]; short8 v; } pf;
      pf.u[0] = (hi < 2) ? a0 : b0;
      pf.u[1] = (hi < 2) ? a1 : b1;
      pf.u[2] = (hi < 2) ? a2 : b2;
      pf.u[3] = (hi < 2) ? a3 : b3;
#pragma unroll
      for (int d = 0; d < 4; ++d) {
        const char* rb = Vbase + (d * 16 + l15) * 128;
        short8 av = *(const short8*)(rb + (((ks * 4 + hi) ^ r7) * 16));
        ot[d] = mfma16(av, pf.v, ot[d]);    // O^T[d][q]
      }
    }
    __builtin_amdgcn_s_setprio(0);
    // trailing barrier: all waves done reading buf[cur] before next iter stages into it
    __builtin_amdgcn_sched_barrier(0);
    asm volatile("" ::: "memory");
    __builtin_amdgcn_s_barrier();
    __builtin_amdgcn_sched_barrier(0);
  }

  // drain remaining loads (tile qt), then the masked diagonal tile
  __builtin_amdgcn_sched_barrier(0);
  asm volatile("s_waitcnt vmcnt(0)" ::: "memory");
  __builtin_amdgcn_s_barrier();
  __builtin_amdgcn_sched_barrier(0);
  {
    const int cur = qt & 1;
    const char* Kbase = (const char*)Ks + cur * 8192;
    const char* Vbase = (const char*)Vs + cur * 8192;
    const int mcmax = w;
    float p[4][4];
#pragma unroll
    for (int mc = 0; mc < 4; ++mc) {
      f32x4 st = {};
      if (mc <= mcmax) {
        const char* rb = Kbase + (mc * 16 + l15) * 128;
        short8 a0 = *(const short8*)(rb + ((hi ^ r7) * 16));
        short8 a1 = *(const short8*)(rb + (((4 + hi) ^ r7) * 16));
        st = mfma16(a0, qf0, st);
        st = mfma16(a1, qf1, st);
      }
#pragma unroll
      for (int r = 0; r < 4; ++r) {
        bool valid = (mc <= mcmax) && ((mc * 16 + hi * 4 + r) <= (w * 16 + l15));
        p[mc][r] = valid ? st[r] * SC : -INFINITY;
      }
    }
    float mt = -INFINITY;
#pragma unroll
    for (int mc = 0; mc < 4; ++mc)
#pragma unroll
      for (int r = 0; r < 4; ++r) mt = fmaxf(mt, p[mc][r]);
    mt = fmaxf(mt, __shfl_xor(mt, 16, 64));
    mt = fmaxf(mt, __shfl_xor(mt, 32, 64));
    const float m_new = fmaxf(m_run, mt);
    const float al = exp2f(m_run - m_new);
    l_run *= al;
#pragma unroll
    for (int d = 0; d < 4; ++d) ot[d] *= al;
    m_run = m_new;
    float ls = 0.0f;
#pragma unroll
    for (int mc = 0; mc < 4; ++mc)
#pragma unroll
      for (int r = 0; r < 4; ++r) { float e = exp2f(p[mc][r] - m_run); p[mc][r] = e; ls += e; }
    ls += __shfl_xor(ls, 16, 64);
    ls += __shfl_xor(ls, 32, 64);
    l_run += ls;
    unsigned pu[4][2];
#pragma unroll
    for (int mc = 0; mc < 4; ++mc) {
      pu[mc][0] = cvt_pk_bf16(p[mc][0], p[mc][1]);
      pu[mc][1] = cvt_pk_bf16(p[mc][2], p[mc][3]);
    }
#pragma unroll
    for (int ks = 0; ks < 2; ++ks) {
      unsigned a0 = (unsigned)__shfl((int)pu[2 * ks][0], srcA, 64);
      unsigned a1 = (unsigned)__shfl((int)pu[2 * ks][1], srcA, 64);
      unsigned a2 = (unsigned)__shfl((int)pu[2 * ks][0], srcB, 64);
      unsigned a3 = (unsigned)__shfl((int)pu[2 * ks][1], srcB, 64);
      unsigned b0 = (unsigned)__shfl((int)pu[2 * ks + 1][0], srcA, 64);
      unsigned b1 = (unsigned)__shfl((int)pu[2 * ks + 1][1], srcA, 64);
      unsigned b2 = (unsigned)__shfl((int)pu[2 * ks + 1][0], srcB, 64);
      unsigned b3 = (unsigned)__shfl((int)pu[2 * ks + 1][1], srcB, 64);
      union { unsigned u[4]; short8 v; } pf;
      pf.u[0] = (hi < 2) ? a0 : b0;
      pf.u[1] = (hi < 2) ? a1 : b1;
      pf.u[2] = (hi < 2) ? a2 : b2;
      pf.u[3] = (hi < 2) ? a3 : b3;
#pragma unroll
      for (int d = 0; d < 4; ++d) {
        const char* rb = Vbase + (d * 16 + l15) * 128;
        short8 av = *(const short8*)(rb + (((ks * 4 + hi) ^ r7) * 16));
        ot[d] = mfma16(av, pf.v, ot[d]);
      }
    }
  }
  const float inv = 1.0f / l_run;
  __hip_bfloat16* Op = Ao + (size_t)(b * SEQ + qrow) * DM + h * 64;
#pragma unroll
  for (int d = 0; d < 4; ++d) {
    uint2 pk;
    pk.x = cvt_pk_bf16(ot[d][0] * inv, ot[d][1] * inv);
    pk.y = cvt_pk_bf16(ot[d][2] * inv, ot[d][3] * inv);
    *(uint2*)(Op + d * 16 + hi * 4) = pk;
  }
}

// ---------------- launch ----------------
extern "C" void kernel_launch(void* const* d_in, const int* in_sizes, int n_in,
                              void* d_out, int out_size, void* d_ws, size_t ws_size,
                              hipStream_t stream) {
  const float* x  = (const float*)d_in[0];
  const float* Wq = (const float*)d_in[1];
  const float* Wk = (const float*)d_in[2];
  const float* Wv = (const float*)d_in[3];
  const float* Wo = (const float*)d_in[4];
  char* ws = (char*)d_ws;
  // ws layout (bytes): [0,8M) xb then reused as attn-out; [8M,16M) Wb (q,k,v,o);
  // [16M,40M) QKV bf16 [4096][3072] (V third unused); [40M,48M) Vt; [48M,48.5M) table
  __hip_bfloat16* xb   = (__hip_bfloat16*)ws;
  __hip_bfloat16* Ao   = (__hip_bfloat16*)ws;                  // aliases xb (dead by then)
  __hip_bfloat16* Wb   = (__hip_bfloat16*)(ws + 8388608);
  __hip_bfloat16* QKVb = (__hip_bfloat16*)(ws + 16777216);
  __hip_bfloat16* Vt   = (__hip_bfloat16*)(ws + 41943040);
  float2*         tab  = (float2*)(ws + 50331648);
  prep_kernel<<<4096, 256, 0, stream>>>(x, Wq, Wk, Wv, Wo, xb, Wb);
  rope_table_kernel<<<256, 256, 0, stream>>>(tab);
  gemm_bt<0, 128, 1><<<dim3(32, 24), 256, 0, stream>>>(xb, Wb, QKVb, 3072, Vt);
  rope_kernel<<<4096, 256, 0, stream>>>(QKVb, tab);
  attn_kernel<<<1024, 256, 0, stream>>>(QKVb, Vt, Ao);
  gemm_bt<1, 64, 0><<<dim3(32, 16), 256, 0, stream>>>(Ao, Wb + 3 * 1048576, d_out, 1024, nullptr);
}

// Round 5
// 199.488 us; speedup vs baseline: 1.0576x; 1.0576x over previous
//
#include <hip/hip_runtime.h>
#include <hip/hip_bf16.h>
#include <stdint.h>
#include <math.h>

#define SEQ 2048
#define DM 1024
#define NH 16
#define DK 64

typedef __attribute__((ext_vector_type(8))) short short8;
typedef __attribute__((ext_vector_type(4))) short short4v;
typedef __attribute__((ext_vector_type(4))) float f32x4;

__device__ __forceinline__ float bf2f(unsigned short s) {
  unsigned u = ((unsigned)s) << 16; float f; __builtin_memcpy(&f, &u, 4); return f;
}
__device__ __forceinline__ unsigned short f2bf(float f) {
  unsigned u; __builtin_memcpy(&u, &f, 4);
  u += 0x7FFFu + ((u >> 16) & 1u);          // RNE
  return (unsigned short)(u >> 16);
}
__device__ __forceinline__ unsigned cvt_pk_bf16(float lo, float hi) {
  unsigned r;
  asm("v_cvt_pk_bf16_f32 %0, %1, %2" : "=v"(r) : "v"(lo), "v"(hi));
  return r;   // [bf16(hi)<<16 | bf16(lo)]
}
__device__ __forceinline__ f32x4 mfma16(short8 a, short8 b, f32x4 c) {
  return __builtin_amdgcn_mfma_f32_16x16x32_bf16(a, b, c, 0, 0, 0);
}
__device__ __forceinline__ void gload_lds16(const void* g, void* l) {
  __builtin_amdgcn_global_load_lds((const __attribute__((address_space(1))) void*)g,
                                   (__attribute__((address_space(3))) void*)l, 16, 0, 0);
}

// ---------------- prep: fp32 -> bf16 for x and the 4 weight matrices ----------------
__global__ __launch_bounds__(256) void prep_kernel(
    const float* __restrict__ x, const float* __restrict__ Wq,
    const float* __restrict__ Wk, const float* __restrict__ Wv,
    const float* __restrict__ Wo, __hip_bfloat16* __restrict__ xb,
    __hip_bfloat16* __restrict__ Wb) {
  int chunk = blockIdx.x * 256 + threadIdx.x;   // 1,048,576 chunks of 8 elems
  const float* src; __hip_bfloat16* dst;
  if (chunk < 524288) { src = x + (size_t)chunk * 8; dst = xb + (size_t)chunk * 8; }
  else {
    int wc = chunk - 524288; int wi = wc >> 17; int wo_ = wc & 131071;
    const float* Ws = (wi == 0) ? Wq : (wi == 1) ? Wk : (wi == 2) ? Wv : Wo;
    src = Ws + (size_t)wo_ * 8; dst = Wb + (size_t)wi * 1048576 + (size_t)wo_ * 8;
  }
  float4 a = *(const float4*)src; float4 b = *(const float4*)(src + 4);
  union { short8 v; unsigned short e[8]; } u;
  u.e[0] = f2bf(a.x); u.e[1] = f2bf(a.y); u.e[2] = f2bf(a.z); u.e[3] = f2bf(a.w);
  u.e[4] = f2bf(b.x); u.e[5] = f2bf(b.y); u.e[6] = f2bf(b.z); u.e[7] = f2bf(b.w);
  *(short8*)dst = u.v;
}

// ---------------- RoPE cos/sin table: [2048][32] float2 ----------------
__global__ __launch_bounds__(256) void rope_table_kernel(float2* __restrict__ tab) {
  int idx = blockIdx.x * 256 + threadIdx.x;   // 65536
  int s = idx >> 5, i = idx & 31;
  float fr = powf(10000.0f, -(float)i * (1.0f / 32.0f));
  float ang = (float)s * fr;
  tab[idx] = make_float2(cosf(ang), sinf(ang));
}

// ============ 256^2 8-phase GEMM (m201 template): C[M][N] = A @ W^T, bf16 ============
// BM=BN=256, BK=64, 8 waves (2M x 4N), 128KB dynamic LDS, counted vmcnt (never 0
// in-loop), per-phase: {ds_read subtile | stage 1 half-tile | vmcnt | bar | mfma | bar}.
// LDS halves per matrix per K-tile: lo=rows 0..127, hi=128..255 (16KB each).
// Stage order per K-tile: [Alo, Blo, Bhi, Ahi]; quadrant order (0,0),(0,1),(1,0),(1,1).
// vmcnt(4) at every phase guarantees: p0's vmcnt -> Bhi landed (read at p1),
// p1's -> Ahi (read p2), p3's -> next tile's Alo+Blo (read at next p0).
__global__ __launch_bounds__(512, 1) void gemm256(
    const __hip_bfloat16* __restrict__ A, const __hip_bfloat16* __restrict__ W,
    __hip_bfloat16* __restrict__ C, const int N) {
  extern __shared__ char lds[];
  char* ldsA = lds;              // 64KB: db(2) x half(2) x 16KB
  char* ldsB = lds + 65536;      // 64KB
  const int t = threadIdx.x;
  int wg = blockIdx.x;
  const int cpx = gridDim.x >> 3;                 // grid % 8 == 0
  wg = (wg & 7) * cpx + (wg >> 3);                // bijective XCD swizzle
  const int ntl = N >> 8;
  const int mt = wg / ntl, nt = wg % ntl;
  const int m0 = mt << 8, n0 = nt << 8;
  const int w = t >> 6, lane = t & 63, l15 = lane & 15, hi = lane >> 4;
  const int wm = w >> 2, wn = w & 3;
  // ---- staging precompute (thread t covers chunks t and t+512 of each 16KB half) ----
  const int lr = t >> 3;
  const int csw = ((t & 7) ^ (lr & 7)) * 8;       // inverse-swizzled source elem offset
  const __hip_bfloat16* aS = A + (size_t)(m0 + lr) * 1024 + csw;
  const __hip_bfloat16* bS = W + (size_t)(n0 + lr) * 1024 + csw;
  char* ldA1 = ldsA + t * 16; char* ldA2 = ldsA + (t + 512) * 16;
  char* ldB1 = ldsB + t * 16; char* ldB2 = ldsB + (t + 512) * 16;
#define STG_A(kt, db, mh) { \
    const __hip_bfloat16* s_ = aS + (size_t)(mh) * 131072 + (kt) * 64; \
    gload_lds16(s_,              ldA1 + (db) * 32768 + (mh) * 16384);  \
    gload_lds16(s_ + 65536,      ldA2 + (db) * 32768 + (mh) * 16384); }
#define STG_B(kt, db, nh) { \
    const __hip_bfloat16* s_ = bS + (size_t)(nh) * 131072 + (kt) * 64; \
    gload_lds16(s_,              ldB1 + (db) * 32768 + (nh) * 16384);  \
    gload_lds16(s_ + 65536,      ldB2 + (db) * 32768 + (nh) * 16384); }
  // ---- read precompute ----
  int lrA[4], lrB[2];
#pragma unroll
  for (int mi = 0; mi < 4; ++mi) lrA[mi] = wm * 64 + mi * 16 + l15;
#pragma unroll
  for (int ni = 0; ni < 2; ++ni) lrB[ni] = wn * 32 + ni * 16 + l15;
  f32x4 acc[8][4] = {};
  short8 afr[4][2], bfr[2][2][2];
  auto rdA = [&](int db, int mh) {
#pragma unroll
    for (int mi = 0; mi < 4; ++mi)
#pragma unroll
      for (int ks = 0; ks < 2; ++ks) {
        int off = db * 32768 + mh * 16384 + lrA[mi] * 128 +
                  ((((ks << 2) + hi) ^ (lrA[mi] & 7)) << 4);
        afr[mi][ks] = *(const short8*)(ldsA + off);
      }
  };
  auto rdB = [&](int db, int nh) {
#pragma unroll
    for (int ni = 0; ni < 2; ++ni)
#pragma unroll
      for (int ks = 0; ks < 2; ++ks) {
        int off = db * 32768 + nh * 16384 + lrB[ni] * 128 +
                  ((((ks << 2) + hi) ^ (lrB[ni] & 7)) << 4);
        bfr[nh][ni][ks] = *(const short8*)(ldsB + off);
      }
  };
  auto quad = [&](int mh, int nh) {
    __builtin_amdgcn_s_setprio(1);
#pragma unroll
    for (int mi = 0; mi < 4; ++mi)
#pragma unroll
      for (int ni = 0; ni < 2; ++ni)
#pragma unroll
        for (int ks = 0; ks < 2; ++ks)
          acc[mh * 4 + mi][nh * 2 + ni] =
              mfma16(afr[mi][ks], bfr[nh][ni][ks], acc[mh * 4 + mi][nh * 2 + ni]);
    __builtin_amdgcn_s_setprio(0);
  };
  // ---- prologue: stage kt=0 (db=0), order [Alo, Blo, Bhi, Ahi] ----
  STG_A(0, 0, 0); STG_B(0, 0, 0); STG_B(0, 0, 1); STG_A(0, 0, 1);
  asm volatile("s_waitcnt vmcnt(4)" ::: "memory");   // Alo,Blo landed
  __builtin_amdgcn_s_barrier();
  // ---- main loop: 16 K-tiles, 4 phases each ----
  for (int kt = 0; kt < 16; ++kt) {
    const int db = kt & 1, dn = db ^ 1;
    const bool nl = (kt < 15);
    // p0: quadrant (0,0)
    rdA(db, 0); rdB(db, 0);
    if (nl) { STG_A(kt + 1, dn, 0);
      asm volatile("s_waitcnt vmcnt(4)" ::: "memory"); }
    else     asm volatile("s_waitcnt vmcnt(2)" ::: "memory");
    __builtin_amdgcn_s_barrier();
    quad(0, 0);
    __builtin_amdgcn_s_barrier();
    // p1: quadrant (0,1)
    rdB(db, 1);
    if (nl) { STG_B(kt + 1, dn, 0);
      asm volatile("s_waitcnt vmcnt(4)" ::: "memory"); }
    else     asm volatile("s_waitcnt vmcnt(0)" ::: "memory");
    __builtin_amdgcn_s_barrier();
    quad(0, 1);
    __builtin_amdgcn_s_barrier();
    // p2: quadrant (1,0)
    rdA(db, 1);
    if (nl) { STG_B(kt + 1, dn, 1);
      asm volatile("s_waitcnt vmcnt(4)" ::: "memory"); }
    __builtin_amdgcn_s_barrier();
    quad(1, 0);
    __builtin_amdgcn_s_barrier();
    // p3: quadrant (1,1) — no new ds_reads
    if (nl) { STG_A(kt + 1, dn, 1);
      asm volatile("s_waitcnt vmcnt(4)" ::: "memory"); }
    __builtin_amdgcn_s_barrier();
    quad(1, 1);
    __builtin_amdgcn_s_barrier();
  }
#undef STG_A
#undef STG_B
  // ---- epilogue ----
  unsigned short* Cb = (unsigned short*)C;
#pragma unroll
  for (int MI = 0; MI < 8; ++MI) {
    const int m = m0 + (MI >> 2) * 128 + wm * 64 + (MI & 3) * 16 + hi * 4;
#pragma unroll
    for (int NI = 0; NI < 4; ++NI) {
      const int n = n0 + (NI >> 1) * 128 + wn * 32 + (NI & 1) * 16 + l15;
#pragma unroll
      for (int r = 0; r < 4; ++r)
        Cb[(size_t)(m + r) * N + n] = f2bf(acc[MI][NI][r]);
    }
  }
}

// ---------------- GEMM 128xBN (out-proj): C fp32 = A[M][1024] @ W[N][1024]^T ----
template<int BN>
__global__ __launch_bounds__(256) void gemm_bt(
    const __hip_bfloat16* __restrict__ A, const __hip_bfloat16* __restrict__ W,
    float* __restrict__ C, const int N) {
  constexpr int NI = BN / 32;
  constexpr int WN = BN / 2;
  __shared__ alignas(16) __hip_bfloat16 As[128 * 32];
  __shared__ alignas(16) __hip_bfloat16 Bs[BN * 32];
  const int t = threadIdx.x;
  const int m0 = blockIdx.x * 128, n0 = blockIdx.y * BN;
  const int w = t >> 6, lane = t & 63, l15 = lane & 15, hi = lane >> 4;
  const int wm = w >> 1, wn = w & 1;
  const int srow = t >> 2, scs = (t & 3) ^ (srow & 3);
  const __hip_bfloat16* aSrcA = A + (size_t)(m0 + srow) * DM + scs * 8;
  const __hip_bfloat16* aSrcB = aSrcA + (size_t)64 * DM;
  const __hip_bfloat16* bSrcA = W + (size_t)(n0 + srow) * DM + scs * 8;
  const __hip_bfloat16* bSrcB = bSrcA + (size_t)64 * DM;
  char* aDstA = (char*)As + t * 16; char* aDstB = (char*)As + (t + 256) * 16;
  char* bDstA = (char*)Bs + t * 16; char* bDstB = (char*)Bs + (t + 256) * 16;
  const int r3 = l15 & 3;
  int aoff[4], boff[NI];
#pragma unroll
  for (int i = 0; i < 4; ++i)
    aoff[i] = (wm * 64 + i * 16 + l15) * 64 + ((hi ^ r3) * 16);
#pragma unroll
  for (int i = 0; i < NI; ++i)
    boff[i] = (wn * WN + i * 16 + l15) * 64 + ((hi ^ r3) * 16);
  f32x4 acc[4][NI] = {};
  for (int kt = 0; kt < DM; kt += 32) {
    gload_lds16(aSrcA + kt, aDstA);
    gload_lds16(aSrcB + kt, aDstB);
    gload_lds16(bSrcA + kt, bDstA);
    if (BN == 128) gload_lds16(bSrcB + kt, bDstB);
    __syncthreads();
    short8 af[4], bfv[NI];
#pragma unroll
    for (int i = 0; i < 4; ++i) af[i] = *(const short8*)((const char*)As + aoff[i]);
#pragma unroll
    for (int i = 0; i < NI; ++i) bfv[i] = *(const short8*)((const char*)Bs + boff[i]);
#pragma unroll
    for (int mi = 0; mi < 4; ++mi)
#pragma unroll
      for (int ni = 0; ni < NI; ++ni)
        acc[mi][ni] = mfma16(af[mi], bfv[ni], acc[mi][ni]);
    __syncthreads();
  }
  const int mBase = m0 + wm * 64, nBase = n0 + wn * WN;
#pragma unroll
  for (int mi = 0; mi < 4; ++mi)
#pragma unroll
    for (int ni = 0; ni < NI; ++ni) {
      int m = mBase + mi * 16 + hi * 4, n = nBase + ni * 16 + l15;
#pragma unroll
      for (int r = 0; r < 4; ++r)
        C[(size_t)(m + r) * N + n] = acc[mi][ni][r];
    }
}

// ---------------- RoPE: rotate Q (cols 0..1023) and K (cols 1024..2047) in place ----
__global__ __launch_bounds__(256) void rope_kernel(
    __hip_bfloat16* __restrict__ QKV, const float2* __restrict__ tab) {
  int chunk = blockIdx.x * 256 + threadIdx.x;   // 4096 rows * 256 chunks
  int row = chunk >> 8; int c0 = (chunk & 255) << 3;
  int s = row & (SEQ - 1);
  const float2* tb = tab + s * 32 + ((c0 & 63) >> 1);
  __hip_bfloat16* p = QKV + (size_t)row * 3072 + c0;
  union { short8 v; unsigned short e[8]; } u; u.v = *(const short8*)p;
  union { short8 v; unsigned short e[8]; } o;
#pragma unroll
  for (int k = 0; k < 4; ++k) {
    float2 cs = tb[k];
    float x1 = bf2f(u.e[2 * k]), x2 = bf2f(u.e[2 * k + 1]);
    o.e[2 * k]     = f2bf(cs.x * x1 - cs.y * x2);
    o.e[2 * k + 1] = f2bf(cs.y * x1 + cs.x * x2);
  }
  *(short8*)p = o.v;
}

// ---------------- V transpose: Vt[bh][d][s] = V[b][s][h*64+d] ----------------
__global__ __launch_bounds__(256) void transpose_v(
    const __hip_bfloat16* __restrict__ QKV, __hip_bfloat16* __restrict__ Vt) {
  const int st = blockIdx.x, bh = blockIdx.y, b = bh >> 4, h = bh & 15;
  __shared__ alignas(16) __hip_bfloat16 tile[64][80];   // pad 16 -> 160B rows
  const int t = threadIdx.x, s0 = st * 64;
#pragma unroll
  for (int i = 0; i < 2; ++i) {
    int idx = i * 256 + t; int r = idx >> 3, c = idx & 7;
    short8 v = *(const short8*)(QKV + (size_t)(b * SEQ + s0 + r) * 3072 + 2048 + h * 64 + c * 8);
    *(short8*)&tile[r][c * 8] = v;
  }
  __syncthreads();
#pragma unroll
  for (int i = 0; i < 2; ++i) {
    int idx = i * 256 + t; int d = idx >> 3, c = idx & 7;
    union { short8 v; short e[8]; } u;
#pragma unroll
    for (int j = 0; j < 8; ++j) u.e[j] = *(short*)&tile[c * 8 + j][d];
    *(short8*)(Vt + ((size_t)bh * 64 + d) * SEQ + s0 + c * 8) = u.v;
  }
}

// ---------------- Flash attention (causal), swapped QK^T, online softmax ----------
__global__ __launch_bounds__(256) void attn_kernel(
    const __hip_bfloat16* __restrict__ QKV, const __hip_bfloat16* __restrict__ Vt,
    __hip_bfloat16* __restrict__ Ao) {
  const int id = blockIdx.x;
  const int bh = (id & 7) * 4 + ((id >> 3) & 3);   // id%8 constant per bh -> same XCD
  const int qt = 31 - (id >> 5);                   // heavy blocks dispatch first
  const int b = bh >> 4, h = bh & 15;
  __shared__ alignas(16) __hip_bfloat16 Ks[2][64 * 64];
  __shared__ alignas(16) __hip_bfloat16 Vs[2][64 * 64];
  const int t = threadIdx.x, w = t >> 6, lane = t & 63, l15 = lane & 15, hi = lane >> 4;
  const int qrow = qt * 64 + w * 16 + l15;
  const __hip_bfloat16* Qp = QKV + (size_t)(b * SEQ + qrow) * 3072 + h * 64 + hi * 8;
  const short8 qf0 = *(const short8*)Qp;          // B-op frag, d = 0..31
  const short8 qf1 = *(const short8*)(Qp + 32);   // d = 32..63
  const int sr = t >> 3, sc = t & 7, scs = sc ^ (sr & 7);
  const __hip_bfloat16* kSrcA = QKV + (size_t)(b * SEQ + sr) * 3072 + DM + h * 64 + scs * 8;
  const __hip_bfloat16* kSrcB = kSrcA + (size_t)32 * 3072;
  const __hip_bfloat16* vSrcA = Vt + ((size_t)bh * 64 + sr) * SEQ + scs * 8;
  const __hip_bfloat16* vSrcB = vSrcA + (size_t)32 * SEQ;
  char* kDstA = (char*)Ks + t * 16;  char* kDstB = (char*)Ks + (t + 256) * 16;
  char* vDstA = (char*)Vs + t * 16;  char* vDstB = (char*)Vs + (t + 256) * 16;
  const int r7 = l15 & 7;
  constexpr float SC = 0.18033688f;        // 0.125 * log2(e)
  constexpr float THR = 11.541560f;        // 8 nats in log2
  f32x4 ot[4] = {};
  float m_run = -INFINITY, l_run = 0.0f;

  gload_lds16(kSrcA, kDstA);
  gload_lds16(kSrcB, kDstB);
  gload_lds16(vSrcA, vDstA);
  gload_lds16(vSrcB, vDstB);

  const int srcA = ((hi & 1) << 5) + l15;
  const int srcB = srcA + 16;

  for (int kvt = 0; kvt < qt; ++kvt) {
    const int cur = kvt & 1;
    const size_t ko = (size_t)((kvt + 1) * 64) * 3072;
    const int vo = (kvt + 1) * 64;
    gload_lds16(kSrcA + ko, kDstA + (cur ^ 1) * 8192);
    gload_lds16(kSrcB + ko, kDstB + (cur ^ 1) * 8192);
    gload_lds16(vSrcA + vo, vDstA + (cur ^ 1) * 8192);
    gload_lds16(vSrcB + vo, vDstB + (cur ^ 1) * 8192);
    __builtin_amdgcn_sched_barrier(0);
    asm volatile("s_waitcnt vmcnt(4)" ::: "memory");
    __builtin_amdgcn_s_barrier();
    __builtin_amdgcn_sched_barrier(0);

    const char* Kbase = (const char*)Ks + cur * 8192;
    const char* Vbase = (const char*)Vs + cur * 8192;
    float p[4][4];
    __builtin_amdgcn_s_setprio(1);
#pragma unroll
    for (int mc = 0; mc < 4; ++mc) {
      const char* rb = Kbase + (mc * 16 + l15) * 128;
      short8 a0 = *(const short8*)(rb + ((hi ^ r7) * 16));
      short8 a1 = *(const short8*)(rb + (((4 + hi) ^ r7) * 16));
      f32x4 st = {};
      st = mfma16(a0, qf0, st);
      st = mfma16(a1, qf1, st);
#pragma unroll
      for (int r = 0; r < 4; ++r) p[mc][r] = st[r] * SC;
    }
    __builtin_amdgcn_s_setprio(0);
    float mt = -INFINITY;
#pragma unroll
    for (int mc = 0; mc < 4; ++mc)
#pragma unroll
      for (int r = 0; r < 4; ++r) mt = fmaxf(mt, p[mc][r]);
    mt = fmaxf(mt, __shfl_xor(mt, 16, 64));
    mt = fmaxf(mt, __shfl_xor(mt, 32, 64));
    if (!__all(mt <= m_run + THR)) {
      const float m_new = fmaxf(m_run, mt);
      const float al = exp2f(m_run - m_new);
      l_run *= al;
#pragma unroll
      for (int d = 0; d < 4; ++d) ot[d] *= al;
      m_run = m_new;
    }
    float ls = 0.0f;
#pragma unroll
    for (int mc = 0; mc < 4; ++mc)
#pragma unroll
      for (int r = 0; r < 4; ++r) { float e = exp2f(p[mc][r] - m_run); p[mc][r] = e; ls += e; }
    ls += __shfl_xor(ls, 16, 64);
    ls += __shfl_xor(ls, 32, 64);
    l_run += ls;
    unsigned pu[4][2];
#pragma unroll
    for (int mc = 0; mc < 4; ++mc) {
      pu[mc][0] = cvt_pk_bf16(p[mc][0], p[mc][1]);
      pu[mc][1] = cvt_pk_bf16(p[mc][2], p[mc][3]);
    }
    __builtin_amdgcn_s_setprio(1);
#pragma unroll
    for (int ks = 0; ks < 2; ++ks) {
      unsigned a0 = (unsigned)__shfl((int)pu[2 * ks][0], srcA, 64);
      unsigned a1 = (unsigned)__shfl((int)pu[2 * ks][1], srcA, 64);
      unsigned a2 = (unsigned)__shfl((int)pu[2 * ks][0], srcB, 64);
      unsigned a3 = (unsigned)__shfl((int)pu[2 * ks][1], srcB, 64);
      unsigned b0 = (unsigned)__shfl((int)pu[2 * ks + 1][0], srcA, 64);
      unsigned b1 = (unsigned)__shfl((int)pu[2 * ks + 1][1], srcA, 64);
      unsigned b2 = (unsigned)__shfl((int)pu[2 * ks + 1][0], srcB, 64);
      unsigned b3 = (unsigned)__shfl((int)pu[2 * ks + 1][1], srcB, 64);
      union { unsigned u[4]; short8 v; } pf;
      pf.u[0] = (hi < 2) ? a0 : b0;
      pf.u[1] = (hi < 2) ? a1 : b1;
      pf.u[2] = (hi < 2) ? a2 : b2;
      pf.u[3] = (hi < 2) ? a3 : b3;
#pragma unroll
      for (int d = 0; d < 4; ++d) {
        const char* rb = Vbase + (d * 16 + l15) * 128;
        short8 av = *(const short8*)(rb + (((ks * 4 + hi) ^ r7) * 16));
        ot[d] = mfma16(av, pf.v, ot[d]);
      }
    }
    __builtin_amdgcn_s_setprio(0);
    __builtin_amdgcn_sched_barrier(0);
    asm volatile("" ::: "memory");
    __builtin_amdgcn_s_barrier();
    __builtin_amdgcn_sched_barrier(0);
  }

  __builtin_amdgcn_sched_barrier(0);
  asm volatile("s_waitcnt vmcnt(0)" ::: "memory");
  __builtin_amdgcn_s_barrier();
  __builtin_amdgcn_sched_barrier(0);
  {
    const int cur = qt & 1;
    const char* Kbase = (const char*)Ks + cur * 8192;
    const char* Vbase = (const char*)Vs + cur * 8192;
    const int mcmax = w;
    float p[4][4];
#pragma unroll
    for (int mc = 0; mc < 4; ++mc) {
      f32x4 st = {};
      if (mc <= mcmax) {
        const char* rb = Kbase + (mc * 16 + l15) * 128;
        short8 a0 = *(const short8*)(rb + ((hi ^ r7) * 16));
        short8 a1 = *(const short8*)(rb + (((4 + hi) ^ r7) * 16));
        st = mfma16(a0, qf0, st);
        st = mfma16(a1, qf1, st);
      }
#pragma unroll
      for (int r = 0; r < 4; ++r) {
        bool valid = (mc <= mcmax) && ((mc * 16 + hi * 4 + r) <= (w * 16 + l15));
        p[mc][r] = valid ? st[r] * SC : -INFINITY;
      }
    }
    float mt = -INFINITY;
#pragma unroll
    for (int mc = 0; mc < 4; ++mc)
#pragma unroll
      for (int r = 0; r < 4; ++r) mt = fmaxf(mt, p[mc][r]);
    mt = fmaxf(mt, __shfl_xor(mt, 16, 64));
    mt = fmaxf(mt, __shfl_xor(mt, 32, 64));
    const float m_new = fmaxf(m_run, mt);
    const float al = exp2f(m_run - m_new);
    l_run *= al;
#pragma unroll
    for (int d = 0; d < 4; ++d) ot[d] *= al;
    m_run = m_new;
    float ls = 0.0f;
#pragma unroll
    for (int mc = 0; mc < 4; ++mc)
#pragma unroll
      for (int r = 0; r < 4; ++r) { float e = exp2f(p[mc][r] - m_run); p[mc][r] = e; ls += e; }
    ls += __shfl_xor(ls, 16, 64);
    ls += __shfl_xor(ls, 32, 64);
    l_run += ls;
    unsigned pu[4][2];
#pragma unroll
    for (int mc = 0; mc < 4; ++mc) {
      pu[mc][0] = cvt_pk_bf16(p[mc][0], p[mc][1]);
      pu[mc][1] = cvt_pk_bf16(p[mc][2], p[mc][3]);
    }
#pragma unroll
    for (int ks = 0; ks < 2; ++ks) {
      unsigned a0 = (unsigned)__shfl((int)pu[2 * ks][0], srcA, 64);
      unsigned a1 = (unsigned)__shfl((int)pu[2 * ks][1], srcA, 64);
      unsigned a2 = (unsigned)__shfl((int)pu[2 * ks][0], srcB, 64);
      unsigned a3 = (unsigned)__shfl((int)pu[2 * ks][1], srcB, 64);
      unsigned b0 = (unsigned)__shfl((int)pu[2 * ks + 1][0], srcA, 64);
      unsigned b1 = (unsigned)__shfl((int)pu[2 * ks + 1][1], srcA, 64);
      unsigned b2 = (unsigned)__shfl((int)pu[2 * ks + 1][0], srcB, 64);
      unsigned b3 = (unsigned)__shfl((int)pu[2 * ks + 1][1], srcB, 64);
      union { unsigned u[4]; short8 v; } pf;
      pf.u[0] = (hi < 2) ? a0 : b0;
      pf.u[1] = (hi < 2) ? a1 : b1;
      pf.u[2] = (hi < 2) ? a2 : b2;
      pf.u[3] = (hi < 2) ? a3 : b3;
#pragma unroll
      for (int d = 0; d < 4; ++d) {
        const char* rb = Vbase + (d * 16 + l15) * 128;
        short8 av = *(const short8*)(rb + (((ks * 4 + hi) ^ r7) * 16));
        ot[d] = mfma16(av, pf.v, ot[d]);
      }
    }
  }
  const float inv = 1.0f / l_run;
  __hip_bfloat16* Op = Ao + (size_t)(b * SEQ + qrow) * DM + h * 64;
#pragma unroll
  for (int d = 0; d < 4; ++d) {
    uint2 pk;
    pk.x = cvt_pk_bf16(ot[d][0] * inv, ot[d][1] * inv);
    pk.y = cvt_pk_bf16(ot[d][2] * inv, ot[d][3] * inv);
    *(uint2*)(Op + d * 16 + hi * 4) = pk;
  }
}

// ---------------- launch ----------------
extern "C" void kernel_launch(void* const* d_in, const int* in_sizes, int n_in,
                              void* d_out, int out_size, void* d_ws, size_t ws_size,
                              hipStream_t stream) {
  const float* x  = (const float*)d_in[0];
  const float* Wq = (const float*)d_in[1];
  const float* Wk = (const float*)d_in[2];
  const float* Wv = (const float*)d_in[3];
  const float* Wo = (const float*)d_in[4];
  char* ws = (char*)d_ws;
  __hip_bfloat16* xb   = (__hip_bfloat16*)ws;
  __hip_bfloat16* Ao   = (__hip_bfloat16*)ws;                  // aliases xb (dead by then)
  __hip_bfloat16* Wb   = (__hip_bfloat16*)(ws + 8388608);
  __hip_bfloat16* QKVb = (__hip_bfloat16*)(ws + 16777216);
  __hip_bfloat16* Vt   = (__hip_bfloat16*)(ws + 41943040);
  float2*         tab  = (float2*)(ws + 50331648);
  (void)hipFuncSetAttribute((const void*)gemm256,
                            hipFuncAttributeMaxDynamicSharedMemorySize, 131072);
  prep_kernel<<<4096, 256, 0, stream>>>(x, Wq, Wk, Wv, Wo, xb, Wb);
  rope_table_kernel<<<256, 256, 0, stream>>>(tab);
  gemm256<<<192, 512, 131072, stream>>>(xb, Wb, QKVb, 3072);
  rope_kernel<<<4096, 256, 0, stream>>>(QKVb, tab);
  transpose_v<<<dim3(32, 32), 256, 0, stream>>>(QKVb, Vt);
  attn_kernel<<<1024, 256, 0, stream>>>(QKVb, Vt, Ao);
  gemm_bt<64><<<dim3(32, 16), 256, 0, stream>>>(Ao, Wb + 3 * 1048576, (float*)d_out, 1024);
}